// Round 1
// 306.132 us; speedup vs baseline: 1.0262x; 1.0262x over previous
//
#include <hip/hip_runtime.h>
#include <hip/hip_bf16.h>
#include <stdint.h>

// LSTMCell fused: gates[8192,4096] = x@Wx^T + h@Wh^T + b as one NT-GEMM
// (M=8192, N=4096 via 4 gate-tiles, K=2048 = concat[x|h]), then elementwise.
// I/O: fp32. Compute: bf16 MFMA 16x16x32 (absmax 0.0156, r2/r3 verified).
//
// r4: main GEMM was at the m97-structure ceiling (898 TF, MfmaUtil 40%,
// 2-barrier-per-K-step with vmcnt(0) drain). Port to the m201 8-phase-style
// schedule: BM=256, BK=32, 8 waves, TRIPLE-buffered LDS (96 KB), counted
// vmcnt(4) once per K-tile (never 0 in steady state), per-phase
// {ds_read || 2x global_load_lds -> barrier -> lgkmcnt(0) -> setprio(1)
//  16 MFMA setprio(0) -> barrier}. T2 already satisfied (pre-packed
// frag-linear chunks, SQ_LDS_BANK_CONFLICT == 0 measured).
#define B_ROWS 8192
#define D_DIM  1024
#define H_DIM  1024
#define K_DIM  2048
#define N_GATES 4096

// fallback (r3) tile params
#define BM 128
#define BN 64
#define BK 64

#define KC (K_DIM / 32)        // 64 k32-chunks = # K-tiles (BK=32 in main)
#define A_M16 (B_ROWS / 16)    // 512 row-chunks
#define W_N16 (N_GATES / 16)   // 256 gate-row-chunks
#define A_CHUNKS (A_M16 * KC)  // 32768
#define W_CHUNKS (W_N16 * KC)  // 16384
#define A_WS_BYTES ((size_t)A_CHUNKS * 1024)
#define W_WS_BYTES ((size_t)W_CHUNKS * 1024)

// main kernel geometry (r4)
#define TBM 256                // rows per block
#define TBH 64                 // h-cols per block (x4 gates = 256 gate cols)
#define NT  KC                 // 64 K-tiles of 32

typedef __bf16 bf16x8 __attribute__((ext_vector_type(8)));
typedef float  f32x4  __attribute__((ext_vector_type(4)));
using bf16_t = __hip_bfloat16;

__device__ __forceinline__ float sigm(float x) {
  return 1.0f / (1.0f + __expf(-x));
}
__device__ __forceinline__ float tanh_fast(float x) {
  return 1.0f - 2.0f / (__expf(2.0f * x) + 1.0f);  // no inf/inf NaN
}

__device__ __forceinline__ void async_ld16(const void* g, void* l) {
  __builtin_amdgcn_global_load_lds(
      (const __attribute__((address_space(1))) unsigned int*)g,
      (__attribute__((address_space(3))) unsigned int*)l, 16, 0, 0);
}

// ---- pack: fp32 inputs -> bf16, MFMA-frag-linear chunks -------------------
// Chunk = 16 rows x 32 k. Element (lane, j): row = base+(lane&15),
// k = kbase + (lane>>4)*8 + j. Stored at chunk*1024B + lane*16B + j*2B.
// This IS the 16x16x32 MFMA A/B operand layout: the main kernel's frag
// read is ds_read_b128 at chunkbase + lane*16: linear, conflict-free.
__global__ void pack_tiles(const float* __restrict__ x,
                           const float* __restrict__ h,
                           const float* __restrict__ Wx,
                           const float* __restrict__ Wh,
                           bf16_t* __restrict__ aws,
                           bf16_t* __restrict__ wws) {
  const int wave = threadIdx.x >> 6, lane = threadIdx.x & 63;
  int c = blockIdx.x * 4 + wave;   // 49152 chunks total, exact grid
  const int r16 = lane & 15, quad = lane >> 4;
  const float* src;
  size_t soff;
  bf16_t* dst;
  if (c < A_CHUNKS) {
    const int m16 = c / KC, k32 = c % KC;
    const int k = k32 * 32 + quad * 8;      // no x/h straddle: 32 | 1024
    src = (k < D_DIM) ? x : h;
    soff = (size_t)(m16 * 16 + r16) * 1024 + (k & 1023);
    dst = aws + (size_t)c * 512;
  } else {
    c -= A_CHUNKS;
    const int n16 = c / KC, k32 = c % KC;
    const int k = k32 * 32 + quad * 8;
    src = (k < D_DIM) ? Wx : Wh;
    soff = (size_t)(n16 * 16 + r16) * 1024 + (k & 1023);
    dst = wws + (size_t)c * 512;
  }
  const f32x4 a = *(const f32x4*)(src + soff);
  const f32x4 b = *(const f32x4*)(src + soff + 4);
  bf16x8 v;
#pragma unroll
  for (int i = 0; i < 4; ++i) { v[i] = (__bf16)a[i]; v[i + 4] = (__bf16)b[i]; }
  *(bf16x8*)(dst + lane * 8) = v;   // 1 KB/wave contiguous store
}

// ---- main: counted-vmcnt phase-pipelined bf16 MFMA GEMM + LSTM epilogue ---
// 8 waves: wave tile = 128 rows x (16 h-cols x 4 gates). acc[g][mi] 128 VGPR.
// LDS: 3 buffers x (16 A-chunks + 16 B-chunks) x 1KB = 96 KB.
// Steady state per tile t: ph0 {read af0..3,bw0..3 | stage A(t+2)},
// ph1 {read af4..7 | stage B(t+2) | vmcnt(4)}. Each phase: barrier,
// lgkmcnt(0), 16 MFMA under setprio(1), barrier.
__global__ __launch_bounds__(512, 2) void lstm_mfma(
    const bf16_t* __restrict__ aws, const bf16_t* __restrict__ wws,
    const float* __restrict__ c_prev, const float* __restrict__ bias,
    float* __restrict__ h_out, float* __restrict__ c_out) {
  __shared__ __align__(16) bf16_t sA[3 * 16 * 512];   // 48 KB
  __shared__ __align__(16) bf16_t sB[3 * 16 * 512];   // 48 KB

  const int tid  = threadIdx.x;
  const int wave = tid >> 6;
  const int lane = tid & 63;

  // XCD-aware swizzle (T1): nwg=512, 512%8==0 -> bijective. m-fastest so
  // each XCD's 64 consecutive work items share 2 B-panels (2 MB, L2-fits).
  int bid = (blockIdx.x & 7) * 64 + (blockIdx.x >> 3);
  const int m0 = (bid & 31) * TBM;
  const int n0 = (bid >> 5) * TBH;
  const int m16_0 = m0 >> 4;
  const int n16_0 = n0 >> 4;

  const int wm = wave >> 2;       // 0..1  (row half)
  const int wh = wave & 3;        // 0..3  (h-col quarter)
  const int lr = lane & 15, quad = lane >> 4;

  f32x4 acc[4][8];
#pragma unroll
  for (int g = 0; g < 4; ++g)
#pragma unroll
    for (int mi = 0; mi < 8; ++mi) {
      f32x4 z = {0.0f, 0.0f, 0.0f, 0.0f};
      acc[g][mi] = z;
    }

  // One global_load_lds per wave per statement: 8 chunks / statement.
  auto stageA = [&](int half, int tt, int pb) {
    const int mi = half * 8 + wave;
    const bf16_t* g = aws + ((size_t)(m16_0 + mi) * KC + tt) * 512 + lane * 8;
    bf16_t* l = sA + ((pb * 16 + mi) * 512) + lane * 8;
    async_ld16(g, l);
  };
  auto stageB = [&](int half, int tt, int pb) {
    const int j = half * 8 + wave;                  // j = g*4 + hc
    const int n16 = (j >> 2) * (H_DIM / 16) + n16_0 + (j & 3);
    const bf16_t* g = wws + ((size_t)n16 * KC + tt) * 512 + lane * 8;
    bf16_t* l = sB + ((pb * 16 + j) * 512) + lane * 8;
    async_ld16(g, l);
  };

  // Prologue: tiles 0 -> buf0, 1 -> buf1 (8 statements/wave in flight).
  stageA(0, 0, 0); stageA(1, 0, 0); stageB(0, 0, 0); stageB(1, 0, 0);
  stageA(0, 1, 1); stageA(1, 1, 1); stageB(0, 1, 1); stageB(1, 1, 1);
  asm volatile("s_waitcnt vmcnt(4)" ::: "memory");   // tile 0 landed
  __builtin_amdgcn_s_barrier();

  int cur = 0;                                       // t % 3
  for (int t = 0; t < NT; ++t) {
    const int pf = (cur == 0) ? 2 : cur - 1;         // (t+2) % 3
    const bf16_t* bufA = sA + cur * (16 * 512);
    const bf16_t* bufB = sB + cur * (16 * 512);
    const bool pre = (t + 2 < NT);

    // ---- phase 0: af[0..3] x bw[0..3] -> acc[g][0..3] ----
    bf16x8 af[4], bw[4];
#pragma unroll
    for (int x = 0; x < 4; ++x)
      af[x] = *(const bf16x8*)&bufA[(wm * 8 + x) * 512 + lane * 8];
#pragma unroll
    for (int g = 0; g < 4; ++g)
      bw[g] = *(const bf16x8*)&bufB[(g * 4 + wh) * 512 + lane * 8];
    if (pre) { stageA(0, t + 2, pf); stageA(1, t + 2, pf); }
    asm volatile("" ::: "memory");
    __builtin_amdgcn_s_barrier();
    asm volatile("s_waitcnt lgkmcnt(0)" ::: "memory");
    __builtin_amdgcn_sched_barrier(0);
    __builtin_amdgcn_s_setprio(1);
#pragma unroll
    for (int g = 0; g < 4; ++g)
#pragma unroll
      for (int x = 0; x < 4; ++x)
        acc[g][x] = __builtin_amdgcn_mfma_f32_16x16x32_bf16(
            af[x], bw[g], acc[g][x], 0, 0, 0);
    __builtin_amdgcn_s_setprio(0);
    asm volatile("" ::: "memory");
    __builtin_amdgcn_s_barrier();

    // ---- phase 1: af[4..7] x bw[0..3] -> acc[g][4..7] ----
#pragma unroll
    for (int x = 0; x < 4; ++x)
      af[x] = *(const bf16x8*)&bufA[(wm * 8 + 4 + x) * 512 + lane * 8];
    if (pre) { stageB(0, t + 2, pf); stageB(1, t + 2, pf); }
    // Counted wait: oldest 4 outstanding = tile t+1's statements (issued
    // two tiles ago); tile t+2's 4 stay in flight. Drain only at the tail.
    if (pre) asm volatile("s_waitcnt vmcnt(4)" ::: "memory");
    else     asm volatile("s_waitcnt vmcnt(0)" ::: "memory");
    asm volatile("" ::: "memory");
    __builtin_amdgcn_s_barrier();
    asm volatile("s_waitcnt lgkmcnt(0)" ::: "memory");
    __builtin_amdgcn_sched_barrier(0);
    __builtin_amdgcn_s_setprio(1);
#pragma unroll
    for (int g = 0; g < 4; ++g)
#pragma unroll
      for (int x = 0; x < 4; ++x)
        acc[g][4 + x] = __builtin_amdgcn_mfma_f32_16x16x32_bf16(
            af[x], bw[g], acc[g][4 + x], 0, 0, 0);
    __builtin_amdgcn_s_setprio(0);
    asm volatile("" ::: "memory");
    __builtin_amdgcn_s_barrier();

    cur = (cur == 2) ? 0 : cur + 1;
  }

  // Epilogue: C/D layout col = lane&15 (gate col), row = quad*4 + reg.
  const int col = n0 + wh * 16 + lr;
  const float bi  = bias[col];
  const float bfv = bias[H_DIM + col];
  const float bo  = bias[2 * H_DIM + col];
  const float bg  = bias[3 * H_DIM + col];
#pragma unroll
  for (int mi = 0; mi < 8; ++mi) {
#pragma unroll
    for (int r = 0; r < 4; ++r) {
      const int m = m0 + wm * 128 + mi * 16 + quad * 4 + r;
      const size_t off = (size_t)m * H_DIM + col;
      const float iv = acc[0][mi][r] + bi;
      const float fv = acc[1][mi][r] + bfv;
      const float ov = acc[2][mi][r] + bo;
      const float gv = acc[3][mi][r] + bg;
      const float cp = c_prev[off];
      const float ct = sigm(fv) * cp + sigm(iv) * tanh_fast(gv);
      h_out[off] = sigm(ov) * tanh_fast(ct);
      c_out[off] = ct;
    }
  }
}

// ---- fallback (r3 kernel): used only if ws_size is too small --------------
__device__ __forceinline__ int sw_(int row, int chunk) {
  return row * BK + ((chunk ^ (row & 7)) << 3);
}

__global__ __launch_bounds__(256, 2) void lstm_f32(
    const float* __restrict__ x, const float* __restrict__ h_prev,
    const float* __restrict__ c_prev, const float* __restrict__ Wx,
    const float* __restrict__ Wh, const float* __restrict__ bias,
    float* __restrict__ h_out, float* __restrict__ c_out) {
  __shared__ bf16_t sA[BM * BK];
  __shared__ bf16_t sB[4 * BN * BK];
  const int tid = threadIdx.x, wave = tid >> 6, lane = tid & 63;
  const int m0 = blockIdx.x * BM, n0 = blockIdx.y * BN;
  const int wm = wave >> 1, wn = wave & 1;
  const int lr = lane & 15, quad = lane >> 4;
  f32x4 acc[4][4][2];
#pragma unroll
  for (int g = 0; g < 4; ++g)
#pragma unroll
    for (int ti = 0; ti < 4; ++ti)
#pragma unroll
      for (int tj = 0; tj < 2; ++tj) {
        f32x4 z = {0.0f, 0.0f, 0.0f, 0.0f};
        acc[g][ti][tj] = z;
      }
  const int srow = lane >> 3, lc = lane & 7, scol = lc << 3;
  for (int k0 = 0; k0 < K_DIM; k0 += BK) {
    const float* aSrc; const float* wSrc; int kh;
    if (k0 < D_DIM) { aSrc = x; wSrc = Wx; kh = k0; }
    else            { aSrc = h_prev; wSrc = Wh; kh = k0 - D_DIM; }
    f32x4 stg[12][2];
#pragma unroll
    for (int t = 0; t < 12; ++t) {
      const int chunk = wave + t * 4;
      const float* g;
      if (chunk < 16) {
        g = aSrc + (size_t)(m0 + chunk * 8 + srow) * 1024 + kh + scol;
      } else {
        const int j = chunk - 16;
        g = wSrc + (size_t)((j >> 3) * H_DIM + n0 + (j & 7) * 8 + srow) * 1024 + kh + scol;
      }
      stg[t][0] = *(const f32x4*)g;
      stg[t][1] = *(const f32x4*)(g + 4);
    }
    __syncthreads();
#pragma unroll
    for (int t = 0; t < 12; ++t) {
      const int chunk = wave + t * 4;
      bf16x8 v;
#pragma unroll
      for (int i = 0; i < 4; ++i) {
        v[i] = (__bf16)stg[t][0][i];
        v[i + 4] = (__bf16)stg[t][1][i];
      }
      bf16_t* dst;
      if (chunk < 16) dst = &sA[sw_(chunk * 8 + srow, lc)];
      else {
        const int j = chunk - 16;
        dst = &sB[(j >> 3) * (BN * BK) + sw_((j & 7) * 8 + srow, lc)];
      }
      *(bf16x8*)dst = v;
    }
    __syncthreads();
#pragma unroll
    for (int kk = 0; kk < BK; kk += 32) {
      const int cbase = kk >> 3;
      bf16x8 af[4];
#pragma unroll
      for (int ti = 0; ti < 4; ++ti)
        af[ti] = *(const bf16x8*)&sA[sw_(wm * 64 + ti * 16 + lr, cbase + quad)];
      bf16x8 bw[4][2];
#pragma unroll
      for (int g = 0; g < 4; ++g)
#pragma unroll
        for (int tj = 0; tj < 2; ++tj)
          bw[g][tj] = *(const bf16x8*)
              &sB[g * (BN * BK) + sw_(wn * 32 + tj * 16 + lr, cbase + quad)];
#pragma unroll
      for (int g = 0; g < 4; ++g)
#pragma unroll
        for (int ti = 0; ti < 4; ++ti)
#pragma unroll
          for (int tj = 0; tj < 2; ++tj)
            acc[g][ti][tj] = __builtin_amdgcn_mfma_f32_16x16x32_bf16(
                af[ti], bw[g][tj], acc[g][ti][tj], 0, 0, 0);
    }
  }
#pragma unroll
  for (int tj = 0; tj < 2; ++tj) {
    const int n = n0 + wn * 32 + tj * 16 + lr;
    const float bi = bias[n], bf = bias[H_DIM + n];
    const float bo = bias[2 * H_DIM + n], bg = bias[3 * H_DIM + n];
#pragma unroll
    for (int ti = 0; ti < 4; ++ti)
#pragma unroll
      for (int r = 0; r < 4; ++r) {
        const int m = m0 + wm * 64 + ti * 16 + quad * 4 + r;
        const size_t off = (size_t)m * H_DIM + n;
        const float iv = acc[0][ti][tj][r] + bi;
        const float fv = acc[1][ti][tj][r] + bf;
        const float ov = acc[2][ti][tj][r] + bo;
        const float gv = acc[3][ti][tj][r] + bg;
        const float cp = c_prev[off];
        const float ct = sigm(fv) * cp + sigm(iv) * tanh_fast(gv);
        h_out[off] = sigm(ov) * tanh_fast(ct);
        c_out[off] = ct;
      }
  }
}

extern "C" void kernel_launch(void* const* d_in, const int* in_sizes, int n_in,
                              void* d_out, int out_size, void* d_ws, size_t ws_size,
                              hipStream_t stream) {
  const float* x      = (const float*)d_in[0];
  const float* h_prev = (const float*)d_in[1];
  const float* c_prev = (const float*)d_in[2];
  const float* Wx     = (const float*)d_in[3];
  const float* Wh     = (const float*)d_in[4];
  const float* b      = (const float*)d_in[5];
  float* h_out = (float*)d_out;
  float* c_out = (float*)d_out + (size_t)B_ROWS * H_DIM;

  if (ws_size >= A_WS_BYTES + W_WS_BYTES) {
    bf16_t* aws = (bf16_t*)d_ws;
    bf16_t* wws = (bf16_t*)((char*)d_ws + A_WS_BYTES);
    pack_tiles<<<(A_CHUNKS + W_CHUNKS) / 4, 256, 0, stream>>>(x, h_prev, Wx, Wh,
                                                              aws, wws);
    const int nblk = (B_ROWS / TBM) * (H_DIM / TBH);   // 512
    lstm_mfma<<<nblk, 512, 0, stream>>>(aws, wws, c_prev, b, h_out, c_out);
  } else {
    dim3 grid(B_ROWS / BM, H_DIM / BN, 1);
    lstm_f32<<<grid, 256, 0, stream>>>(x, h_prev, c_prev, Wx, Wh, b, h_out, c_out);
  }
}

// Round 3
// 297.699 us; speedup vs baseline: 1.0553x; 1.0283x over previous
//
#include <hip/hip_runtime.h>
#include <hip/hip_bf16.h>
#include <stdint.h>

// LSTMCell fused: gates[8192,4096] = x@Wx^T + h@Wh^T + b as one NT-GEMM
// (M=8192, N=4096 via 4 gate-tiles, K=2048 = concat[x|h]), then elementwise.
// I/O: fp32. Compute: bf16 MFMA 16x16x32 (absmax 0.0156, r2/r3/r4 verified).
//
// r6 == r5 resubmitted (round-2 bench was an infra container failure, not a
// kernel result; audit found no hang-capable defect: barriers balanced,
// vmcnt tail drains monotonically, no OOB, 128KB LDS within 160KB).
//
// r5 rationale: r4's 8-phase port regressed (167us, MfmaUtil 36%) because
// (a) the XCD swizzle used 32m x 2n regions -> every XCD pulled ALL of A
// through its L2 (FETCH 287MB vs 116MB), turning staging loads into L2
// misses; (b) prefetch distance 2 (~650cyc issue-to-wait) doesn't cover miss
// latency, and with 1 block/CU every vmcnt stall drains the whole CU.
// Fix: bijective 8m x 8n per-XCD regions (optimal fetch = A*2 + W*4 ~ 128MB)
// + QUAD-buffered LDS (128KB), prefetch distance 3, steady-state vmcnt(8).
#define B_ROWS 8192
#define D_DIM  1024
#define H_DIM  1024
#define K_DIM  2048
#define N_GATES 4096

// fallback (r3) tile params
#define BM 128
#define BN 64
#define BK 64

#define KC (K_DIM / 32)        // 64 k32-chunks = # K-tiles (BK=32 in main)
#define A_M16 (B_ROWS / 16)    // 512 row-chunks
#define W_N16 (N_GATES / 16)   // 256 gate-row-chunks
#define A_CHUNKS (A_M16 * KC)  // 32768
#define W_CHUNKS (W_N16 * KC)  // 16384
#define A_WS_BYTES ((size_t)A_CHUNKS * 1024)
#define W_WS_BYTES ((size_t)W_CHUNKS * 1024)

// main kernel geometry
#define TBM 256                // rows per block
#define TBH 64                 // h-cols per block (x4 gates = 256 gate cols)
#define NT  KC                 // 64 K-tiles of 32
#define NBUF 4                 // LDS pipeline depth (prefetch distance 3)

typedef __bf16 bf16x8 __attribute__((ext_vector_type(8)));
typedef float  f32x4  __attribute__((ext_vector_type(4)));
using bf16_t = __hip_bfloat16;

__device__ __forceinline__ float sigm(float x) {
  return 1.0f / (1.0f + __expf(-x));
}
__device__ __forceinline__ float tanh_fast(float x) {
  return 1.0f - 2.0f / (__expf(2.0f * x) + 1.0f);  // no inf/inf NaN
}

__device__ __forceinline__ void async_ld16(const void* g, void* l) {
  __builtin_amdgcn_global_load_lds(
      (const __attribute__((address_space(1))) unsigned int*)g,
      (__attribute__((address_space(3))) unsigned int*)l, 16, 0, 0);
}

// ---- pack: fp32 inputs -> bf16, MFMA-frag-linear chunks -------------------
// Chunk = 16 rows x 32 k. Element (lane, j): row = base+(lane&15),
// k = kbase + (lane>>4)*8 + j. Stored at chunk*1024B + lane*16B + j*2B.
// This IS the 16x16x32 MFMA A/B operand layout: the main kernel's frag
// read is ds_read_b128 at chunkbase + lane*16: linear, conflict-free.
__global__ void pack_tiles(const float* __restrict__ x,
                           const float* __restrict__ h,
                           const float* __restrict__ Wx,
                           const float* __restrict__ Wh,
                           bf16_t* __restrict__ aws,
                           bf16_t* __restrict__ wws) {
  const int wave = threadIdx.x >> 6, lane = threadIdx.x & 63;
  int c = blockIdx.x * 4 + wave;   // 49152 chunks total, exact grid
  const int r16 = lane & 15, quad = lane >> 4;
  const float* src;
  size_t soff;
  bf16_t* dst;
  if (c < A_CHUNKS) {
    const int m16 = c / KC, k32 = c % KC;
    const int k = k32 * 32 + quad * 8;      // no x/h straddle: 32 | 1024
    src = (k < D_DIM) ? x : h;
    soff = (size_t)(m16 * 16 + r16) * 1024 + (k & 1023);
    dst = aws + (size_t)c * 512;
  } else {
    c -= A_CHUNKS;
    const int n16 = c / KC, k32 = c % KC;
    const int k = k32 * 32 + quad * 8;
    src = (k < D_DIM) ? Wx : Wh;
    soff = (size_t)(n16 * 16 + r16) * 1024 + (k & 1023);
    dst = wws + (size_t)c * 512;
  }
  const f32x4 a = *(const f32x4*)(src + soff);
  const f32x4 b = *(const f32x4*)(src + soff + 4);
  bf16x8 v;
#pragma unroll
  for (int i = 0; i < 4; ++i) { v[i] = (__bf16)a[i]; v[i + 4] = (__bf16)b[i]; }
  *(bf16x8*)(dst + lane * 8) = v;   // 1 KB/wave contiguous store
}

// ---- main: counted-vmcnt phase-pipelined bf16 MFMA GEMM + LSTM epilogue ---
// 8 waves: wave tile = 128 rows x (16 h-cols x 4 gates). acc[g][mi] 128 VGPR.
// LDS: 4 buffers x (16 A-chunks + 16 B-chunks) x 1KB = 128 KB, 1 block/CU.
// Steady state per tile t: ph0 {read af0..3,bw0..3 | stage A(t+3)},
// ph1 {read af4..7 | stage B(t+3) | vmcnt(8): t+1 landed, t+2/t+3 in
// flight}. Each phase: barrier, lgkmcnt(0), 16 MFMA under setprio(1),
// barrier. vmcnt never drains to 0 until the last 2 tiles.
__global__ __launch_bounds__(512, 2) void lstm_mfma(
    const bf16_t* __restrict__ aws, const bf16_t* __restrict__ wws,
    const float* __restrict__ c_prev, const float* __restrict__ bias,
    float* __restrict__ h_out, float* __restrict__ c_out) {
  __shared__ __align__(16) bf16_t sA[NBUF * 16 * 512];   // 64 KB
  __shared__ __align__(16) bf16_t sB[NBUF * 16 * 512];   // 64 KB

  const int tid  = threadIdx.x;
  const int wave = tid >> 6;
  const int lane = tid & 63;

  // XCD mapping (T1, bijective): 8 regions of 8m x 8n blocks (4 along m,
  // 2 along n). Per-XCD fetch footprint: A 8MB + W 8MB, streamed in 256KB
  // k-slices through the 4MB L2. Total ideal fetch = A*2 + W*4 = 128MB
  // (vs r4's 32m x 2n regions = A*8 = 287MB measured).
  const int xcd = blockIdx.x & 7;
  const int idx = blockIdx.x >> 3;                  // 0..63 within region
  const int m_blk = (xcd >> 1) * 8 + (idx & 7);     // 0..31
  const int n_blk = (xcd & 1) * 8 + (idx >> 3);     // 0..15
  const int m0 = m_blk * TBM;
  const int n0 = n_blk * TBH;
  const int m16_0 = m0 >> 4;
  const int n16_0 = n0 >> 4;

  const int wm = wave >> 2;       // 0..1  (row half)
  const int wh = wave & 3;        // 0..3  (h-col quarter)
  const int lr = lane & 15, quad = lane >> 4;

  f32x4 acc[4][8];
#pragma unroll
  for (int g = 0; g < 4; ++g)
#pragma unroll
    for (int mi = 0; mi < 8; ++mi) {
      f32x4 z = {0.0f, 0.0f, 0.0f, 0.0f};
      acc[g][mi] = z;
    }

  // One global_load_lds per wave per statement: 8 chunks / statement.
  auto stageA = [&](int half, int tt, int pb) {
    const int mi = half * 8 + wave;
    const bf16_t* g = aws + ((size_t)(m16_0 + mi) * KC + tt) * 512 + lane * 8;
    bf16_t* l = sA + ((pb * 16 + mi) * 512) + lane * 8;
    async_ld16(g, l);
  };
  auto stageB = [&](int half, int tt, int pb) {
    const int j = half * 8 + wave;                  // j = g*4 + hc
    const int n16 = (j >> 2) * (H_DIM / 16) + n16_0 + (j & 3);
    const bf16_t* g = wws + ((size_t)n16 * KC + tt) * 512 + lane * 8;
    bf16_t* l = sB + ((pb * 16 + j) * 512) + lane * 8;
    async_ld16(g, l);
  };

  // Prologue: tiles 0,1,2 -> bufs 0,1,2 (12 statements/wave in flight).
  stageA(0, 0, 0); stageA(1, 0, 0); stageB(0, 0, 0); stageB(1, 0, 0);
  stageA(0, 1, 1); stageA(1, 1, 1); stageB(0, 1, 1); stageB(1, 1, 1);
  stageA(0, 2, 2); stageA(1, 2, 2); stageB(0, 2, 2); stageB(1, 2, 2);
  asm volatile("s_waitcnt vmcnt(8)" ::: "memory");   // tile 0 landed
  __builtin_amdgcn_s_barrier();

  for (int t = 0; t < NT; ++t) {
    const int cur = t & 3;
    const int pf  = (t + 3) & 3;
    const bf16_t* bufA = sA + cur * (16 * 512);
    const bf16_t* bufB = sB + cur * (16 * 512);
    const bool pre = (t + 3 < NT);

    // ---- phase 0: af[0..3] x bw[0..3] -> acc[g][0..3] ----
    bf16x8 af[4], bw[4];
#pragma unroll
    for (int x = 0; x < 4; ++x)
      af[x] = *(const bf16x8*)&bufA[(wm * 8 + x) * 512 + lane * 8];
#pragma unroll
    for (int g = 0; g < 4; ++g)
      bw[g] = *(const bf16x8*)&bufB[(g * 4 + wh) * 512 + lane * 8];
    if (pre) { stageA(0, t + 3, pf); stageA(1, t + 3, pf); }
    asm volatile("" ::: "memory");
    __builtin_amdgcn_s_barrier();
    asm volatile("s_waitcnt lgkmcnt(0)" ::: "memory");
    __builtin_amdgcn_sched_barrier(0);
    __builtin_amdgcn_s_setprio(1);
#pragma unroll
    for (int g = 0; g < 4; ++g)
#pragma unroll
      for (int x = 0; x < 4; ++x)
        acc[g][x] = __builtin_amdgcn_mfma_f32_16x16x32_bf16(
            af[x], bw[g], acc[g][x], 0, 0, 0);
    __builtin_amdgcn_s_setprio(0);
    asm volatile("" ::: "memory");
    __builtin_amdgcn_s_barrier();

    // ---- phase 1: af[4..7] x bw[0..3] -> acc[g][4..7] ----
#pragma unroll
    for (int x = 0; x < 4; ++x)
      af[x] = *(const bf16x8*)&bufA[(wm * 8 + 4 + x) * 512 + lane * 8];
    if (pre) { stageB(0, t + 3, pf); stageB(1, t + 3, pf); }
    // Counted wait: need tile t+1 fully landed before the closing barrier.
    // Steady state: outstanding = {t+1, t+2, t+3} x4 -> vmcnt(8) leaves
    // t+2/t+3 (8 loads) in flight. Tail drains 4 -> 0 -> skip.
    if (t + 3 < NT)      asm volatile("s_waitcnt vmcnt(8)" ::: "memory");
    else if (t + 2 < NT) asm volatile("s_waitcnt vmcnt(4)" ::: "memory");
    else if (t + 1 < NT) asm volatile("s_waitcnt vmcnt(0)" ::: "memory");
    asm volatile("" ::: "memory");
    __builtin_amdgcn_s_barrier();
    asm volatile("s_waitcnt lgkmcnt(0)" ::: "memory");
    __builtin_amdgcn_sched_barrier(0);
    __builtin_amdgcn_s_setprio(1);
#pragma unroll
    for (int g = 0; g < 4; ++g)
#pragma unroll
      for (int x = 0; x < 4; ++x)
        acc[g][4 + x] = __builtin_amdgcn_mfma_f32_16x16x32_bf16(
            af[x], bw[g], acc[g][4 + x], 0, 0, 0);
    __builtin_amdgcn_s_setprio(0);
    asm volatile("" ::: "memory");
    __builtin_amdgcn_s_barrier();
  }

  // Epilogue: C/D layout col = lane&15 (gate col), row = quad*4 + reg.
  const int col = n0 + wh * 16 + lr;
  const float bi  = bias[col];
  const float bfv = bias[H_DIM + col];
  const float bo  = bias[2 * H_DIM + col];
  const float bg  = bias[3 * H_DIM + col];
#pragma unroll
  for (int mi = 0; mi < 8; ++mi) {
#pragma unroll
    for (int r = 0; r < 4; ++r) {
      const int m = m0 + wm * 128 + mi * 16 + quad * 4 + r;
      const size_t off = (size_t)m * H_DIM + col;
      const float iv = acc[0][mi][r] + bi;
      const float fv = acc[1][mi][r] + bfv;
      const float ov = acc[2][mi][r] + bo;
      const float gv = acc[3][mi][r] + bg;
      const float cp = c_prev[off];
      const float ct = sigm(fv) * cp + sigm(iv) * tanh_fast(gv);
      h_out[off] = sigm(ov) * tanh_fast(ct);
      c_out[off] = ct;
    }
  }
}

// ---- fallback (r3 kernel): used only if ws_size is too small --------------
__device__ __forceinline__ int sw_(int row, int chunk) {
  return row * BK + ((chunk ^ (row & 7)) << 3);
}

__global__ __launch_bounds__(256, 2) void lstm_f32(
    const float* __restrict__ x, const float* __restrict__ h_prev,
    const float* __restrict__ c_prev, const float* __restrict__ Wx,
    const float* __restrict__ Wh, const float* __restrict__ bias,
    float* __restrict__ h_out, float* __restrict__ c_out) {
  __shared__ bf16_t sA[BM * BK];
  __shared__ bf16_t sB[4 * BN * BK];
  const int tid = threadIdx.x, wave = tid >> 6, lane = tid & 63;
  const int m0 = blockIdx.x * BM, n0 = blockIdx.y * BN;
  const int wm = wave >> 1, wn = wave & 1;
  const int lr = lane & 15, quad = lane >> 4;
  f32x4 acc[4][4][2];
#pragma unroll
  for (int g = 0; g < 4; ++g)
#pragma unroll
    for (int ti = 0; ti < 4; ++ti)
#pragma unroll
      for (int tj = 0; tj < 2; ++tj) {
        f32x4 z = {0.0f, 0.0f, 0.0f, 0.0f};
        acc[g][ti][tj] = z;
      }
  const int srow = lane >> 3, lc = lane & 7, scol = lc << 3;
  for (int k0 = 0; k0 < K_DIM; k0 += BK) {
    const float* aSrc; const float* wSrc; int kh;
    if (k0 < D_DIM) { aSrc = x; wSrc = Wx; kh = k0; }
    else            { aSrc = h_prev; wSrc = Wh; kh = k0 - D_DIM; }
    f32x4 stg[12][2];
#pragma unroll
    for (int t = 0; t < 12; ++t) {
      const int chunk = wave + t * 4;
      const float* g;
      if (chunk < 16) {
        g = aSrc + (size_t)(m0 + chunk * 8 + srow) * 1024 + kh + scol;
      } else {
        const int j = chunk - 16;
        g = wSrc + (size_t)((j >> 3) * H_DIM + n0 + (j & 7) * 8 + srow) * 1024 + kh + scol;
      }
      stg[t][0] = *(const f32x4*)g;
      stg[t][1] = *(const f32x4*)(g + 4);
    }
    __syncthreads();
#pragma unroll
    for (int t = 0; t < 12; ++t) {
      const int chunk = wave + t * 4;
      bf16x8 v;
#pragma unroll
      for (int i = 0; i < 4; ++i) {
        v[i] = (__bf16)stg[t][0][i];
        v[i + 4] = (__bf16)stg[t][1][i];
      }
      bf16_t* dst;
      if (chunk < 16) dst = &sA[sw_(chunk * 8 + srow, lc)];
      else {
        const int j = chunk - 16;
        dst = &sB[(j >> 3) * (BN * BK) + sw_((j & 7) * 8 + srow, lc)];
      }
      *(bf16x8*)dst = v;
    }
    __syncthreads();
#pragma unroll
    for (int kk = 0; kk < BK; kk += 32) {
      const int cbase = kk >> 3;
      bf16x8 af[4];
#pragma unroll
      for (int ti = 0; ti < 4; ++ti)
        af[ti] = *(const bf16x8*)&sA[sw_(wm * 64 + ti * 16 + lr, cbase + quad)];
      bf16x8 bw[4][2];
#pragma unroll
      for (int g = 0; g < 4; ++g)
#pragma unroll
        for (int tj = 0; tj < 2; ++tj)
          bw[g][tj] = *(const bf16x8*)
              &sB[g * (BN * BK) + sw_(wn * 32 + tj * 16 + lr, cbase + quad)];
#pragma unroll
      for (int g = 0; g < 4; ++g)
#pragma unroll
        for (int ti = 0; ti < 4; ++ti)
#pragma unroll
          for (int tj = 0; tj < 2; ++tj)
            acc[g][ti][tj] = __builtin_amdgcn_mfma_f32_16x16x32_bf16(
                af[ti], bw[g][tj], acc[g][ti][tj], 0, 0, 0);
    }
  }
#pragma unroll
  for (int tj = 0; tj < 2; ++tj) {
    const int n = n0 + wn * 32 + tj * 16 + lr;
    const float bi = bias[n], bf = bias[H_DIM + n];
    const float bo = bias[2 * H_DIM + n], bg = bias[3 * H_DIM + n];
#pragma unroll
    for (int ti = 0; ti < 4; ++ti)
#pragma unroll
      for (int r = 0; r < 4; ++r) {
        const int m = m0 + wm * 64 + ti * 16 + quad * 4 + r;
        const size_t off = (size_t)m * H_DIM + n;
        const float iv = acc[0][ti][tj][r] + bi;
        const float fv = acc[1][ti][tj][r] + bf;
        const float ov = acc[2][ti][tj][r] + bo;
        const float gv = acc[3][ti][tj][r] + bg;
        const float cp = c_prev[off];
        const float ct = sigm(fv) * cp + sigm(iv) * tanh_fast(gv);
        h_out[off] = sigm(ov) * tanh_fast(ct);
        c_out[off] = ct;
      }
  }
}

extern "C" void kernel_launch(void* const* d_in, const int* in_sizes, int n_in,
                              void* d_out, int out_size, void* d_ws, size_t ws_size,
                              hipStream_t stream) {
  const float* x      = (const float*)d_in[0];
  const float* h_prev = (const float*)d_in[1];
  const float* c_prev = (const float*)d_in[2];
  const float* Wx     = (const float*)d_in[3];
  const float* Wh     = (const float*)d_in[4];
  const float* b      = (const float*)d_in[5];
  float* h_out = (float*)d_out;
  float* c_out = (float*)d_out + (size_t)B_ROWS * H_DIM;

  if (ws_size >= A_WS_BYTES + W_WS_BYTES) {
    bf16_t* aws = (bf16_t*)d_ws;
    bf16_t* wws = (bf16_t*)((char*)d_ws + A_WS_BYTES);
    pack_tiles<<<(A_CHUNKS + W_CHUNKS) / 4, 256, 0, stream>>>(x, h_prev, Wx, Wh,
                                                              aws, wws);
    const int nblk = (B_ROWS / TBM) * (H_DIM / TBH);   // 512
    lstm_mfma<<<nblk, 512, 0, stream>>>(aws, wws, c_prev, b, h_out, c_out);
  } else {
    dim3 grid(B_ROWS / BM, H_DIM / BN, 1);
    lstm_f32<<<grid, 256, 0, stream>>>(x, h_prev, c_prev, Wx, Wh, b, h_out, c_out);
  }
}